// Round 1
// baseline (304.774 us; speedup 1.0000x reference)
//
#include <hip/hip_runtime.h>

// GestureRNN v9: register-resident recurrent state + DPP row-rotate all-gather.
// B=4096, T=512, IN=10, H=32, NCLS=9.
//
// v8 post-mortem (275.9 us): step chain ~1200 cyc vs ~260 cyc issue floor at
// 1 wave/SIMD -> latency-bound on the LDS state round-trip (ds_write h ->
// in-order DS pipe -> 8x ds_read_b128 -> unpack). v9 deletes state LDS
// entirely: each batch slot's 16 lanes are one DPP row; lane's new state is
// one packed half2 (its 2 units). All-gather = 15 INDEPENDENT
// v_mov_b32_dpp row_ror:k (depth-1, VALU pipe, no lgkmcnt). The fixed
// rotation permutation is baked into the per-lane weight register preload;
// rotation DIRECTION is probed at runtime (rotate lane-id once, derive stp)
// so weight indexing is correct for either row_ror convention.
// x stays in LDS tiles (broadcast reads, off the recurrence chain).
// Core: 4 batches/wave, lane owns units {2u,2u+1}, f16 state + fdot2,
// layer-pipelined (step t computes h1[t] and h2[t-1]).

constexpr int T_  = 512;
constexpr int IN_ = 10;
constexpr int H_  = 32;
constexpr int NC_ = 9;
constexpr int XS_ = 12;    // x slot stride, floats (48 B, 16B-aligned slots)
constexpr int XB_ = 196;   // x buffer per batch, floats (16*12 + 4 pad)
constexpr int XT_ = 16;    // timesteps per x tile

typedef _Float16 h2v __attribute__((ext_vector_type(2)));

__device__ __forceinline__ void cfence() { __asm__ volatile("" ::: "memory"); }

// Row-rotate by K within each DPP row of 16 lanes (VALU, no DS pipe).
template <int K>
__device__ __forceinline__ h2v rotk(h2v v) {
    int r = __builtin_amdgcn_update_dpp(
        0, __builtin_bit_cast(int, v), 0x120 + K, 0xF, 0xF, false);
    return __builtin_bit_cast(h2v, r);
}

// All-gather: d[k] = packed pair of row-lane (u + stp*k) & 15.
#define GATH(d, s)                                                        \
    d[0]  = (s);          d[1]  = rotk<1>(s);   d[2]  = rotk<2>(s);       \
    d[3]  = rotk<3>(s);   d[4]  = rotk<4>(s);   d[5]  = rotk<5>(s);       \
    d[6]  = rotk<6>(s);   d[7]  = rotk<7>(s);   d[8]  = rotk<8>(s);       \
    d[9]  = rotk<9>(s);   d[10] = rotk<10>(s);  d[11] = rotk<11>(s);      \
    d[12] = rotk<12>(s);  d[13] = rotk<13>(s);  d[14] = rotk<14>(s);      \
    d[15] = rotk<15>(s);

__global__ __launch_bounds__(64, 1) void gesture_rnn_kernel(
    const float* __restrict__ x,      // [B, T, IN]
    const float* __restrict__ W_ih0,  // [H, IN]
    const float* __restrict__ W_hh0,  // [H, H]
    const float* __restrict__ b_ih0,  // [H]
    const float* __restrict__ b_hh0,  // [H]
    const float* __restrict__ W_ih1,  // [H, H]
    const float* __restrict__ W_hh1,  // [H, H]
    const float* __restrict__ b_ih1,  // [H]
    const float* __restrict__ b_hh1,  // [H]
    const float* __restrict__ W_fc,   // [NC, H]
    const float* __restrict__ b_fc,   // [NC]
    float* __restrict__ out)          // [B, NC]
{
    const int lane = threadIdx.x;     // 0..63
    const int bs   = lane >> 4;       // batch slot within wave: 0..3
    const int u    = lane & 15;       // unit-pair index: owns units 2u, 2u+1
    const long b   = (long)blockIdx.x * 4 + bs;
    const int jA   = 2 * u, jB = 2 * u + 1;

    // ---- runtime direction probe for row_ror (direction-proof weights) ----
    // pr = u-value of the row-lane that rotk<1> sources from.
    const int pr  = __builtin_amdgcn_update_dpp(0, u, 0x121, 0xF, 0xF, false);
    const int stp = (pr - u) & 15;    // 1 or 15, uniform within the row

    // ---- fp32 x-projection weights for both owned units ----
    float wxA[IN_], wxB[IN_];
#pragma unroll
    for (int i = 0; i < IN_; ++i) {
        wxA[i] = W_ih0[jA * IN_ + i];
        wxB[i] = W_ih0[jB * IN_ + i];
    }

    // ---- half2-packed recurrent weights, permuted to match the gather:
    //      slot k must multiply the pair of row-lane s = (u + stp*k) & 15 ----
    h2v w0a[16], w0b[16], w1a[16], w1b[16], w2a[16], w2b[16];
#pragma unroll
    for (int k = 0; k < 16; ++k) {
        const int s = (u + stp * k) & 15;
        w0a[k][0] = (_Float16)W_hh0[jA * H_ + 2 * s];
        w0a[k][1] = (_Float16)W_hh0[jA * H_ + 2 * s + 1];
        w0b[k][0] = (_Float16)W_hh0[jB * H_ + 2 * s];
        w0b[k][1] = (_Float16)W_hh0[jB * H_ + 2 * s + 1];
        w1a[k][0] = (_Float16)W_ih1[jA * H_ + 2 * s];
        w1a[k][1] = (_Float16)W_ih1[jA * H_ + 2 * s + 1];
        w1b[k][0] = (_Float16)W_ih1[jB * H_ + 2 * s];
        w1b[k][1] = (_Float16)W_ih1[jB * H_ + 2 * s + 1];
        w2a[k][0] = (_Float16)W_hh1[jA * H_ + 2 * s];
        w2a[k][1] = (_Float16)W_hh1[jA * H_ + 2 * s + 1];
        w2b[k][0] = (_Float16)W_hh1[jB * H_ + 2 * s];
        w2b[k][1] = (_Float16)W_hh1[jB * H_ + 2 * s + 1];
    }
    const float bias0A = b_ih0[jA] + b_hh0[jA];
    const float bias0B = b_ih0[jB] + b_hh0[jB];
    const float bias1A = b_ih1[jA] + b_hh1[jA];
    const float bias1B = b_ih1[jB] + b_hh1[jB];

    __shared__ __align__(16) float xtile[4][XB_];     // current x tile
    __shared__ __align__(4) _Float16 hfin[4][H_];     // h2[511] for FC head

    // ---- x tile machinery: lane u owns timestep (16*nt + u) of batch b ----
    const float* xg = x + ((size_t)b * T_ + u) * IN_;
    float xr[IN_];
#pragma unroll
    for (int i = 0; i < IN_; i += 2) {                // load tile 0
        float2 v = *(const float2*)(xg + i);
        xr[i] = v.x; xr[i + 1] = v.y;
    }
    xg += XT_ * IN_;

#define STAGE(PREFETCH)                                                      \
    {                                                                        \
        float* dst_ = &xtile[bs][u * XS_];                                   \
        *(float4*)(dst_)     = make_float4(xr[0], xr[1], xr[2], xr[3]);      \
        *(float4*)(dst_ + 4) = make_float4(xr[4], xr[5], xr[6], xr[7]);      \
        *(float2*)(dst_ + 8) = make_float2(xr[8], xr[9]);                    \
        if (PREFETCH) {                                                      \
            _Pragma("unroll")                                                \
            for (int i_ = 0; i_ < IN_; i_ += 2) {                            \
                float2 v_ = *(const float2*)(xg + i_);                       \
                xr[i_] = v_.x; xr[i_ + 1] = v_.y;                            \
            }                                                                \
            xg += XT_ * IN_;                                                 \
        }                                                                    \
        cfence();                                                            \
    }

    // Register-resident state: packed pairs for this lane's 2 units.
    h2v p1, p2;

#define STEP(TT)                                                             \
    {                                                                        \
        h2v h1h[16], h2h[16];                                                \
        GATH(h1h, p1)                                                        \
        GATH(h2h, p2)                                                        \
        const float* xs_ = &xtile[bs][((TT) & 15) * XS_];                    \
        const float4 xv0_ = *(const float4*)(xs_);                           \
        const float4 xv1_ = *(const float4*)(xs_ + 4);                       \
        const float2 xv2_ = *(const float2*)(xs_ + 8);                       \
        const float xvv_[10] = {xv0_.x, xv0_.y, xv0_.z, xv0_.w,              \
                                xv1_.x, xv1_.y, xv1_.z, xv1_.w,              \
                                xv2_.x, xv2_.y};                             \
        float a1A0 = bias0A, a1A1 = 0.f, a1B0 = bias0B, a1B1 = 0.f;          \
        _Pragma("unroll")                                                    \
        for (int i_ = 0; i_ < IN_; i_ += 2) {                                \
            a1A0 = fmaf(wxA[i_],     xvv_[i_],     a1A0);                    \
            a1A1 = fmaf(wxA[i_ + 1], xvv_[i_ + 1], a1A1);                    \
            a1B0 = fmaf(wxB[i_],     xvv_[i_],     a1B0);                    \
            a1B1 = fmaf(wxB[i_ + 1], xvv_[i_ + 1], a1B1);                    \
        }                                                                    \
        float a2A0 = bias1A, a2A1 = 0.f, a2A2 = 0.f, a2A3 = 0.f;             \
        float a2B0 = bias1B, a2B1 = 0.f, a2B2 = 0.f, a2B3 = 0.f;             \
        _Pragma("unroll")                                                    \
        for (int k_ = 0; k_ < 8; ++k_) {                                     \
            a1A0 = __builtin_amdgcn_fdot2(w0a[k_],   h1h[k_],   a1A0, false);\
            a1A1 = __builtin_amdgcn_fdot2(w0a[k_+8], h1h[k_+8], a1A1, false);\
            a1B0 = __builtin_amdgcn_fdot2(w0b[k_],   h1h[k_],   a1B0, false);\
            a1B1 = __builtin_amdgcn_fdot2(w0b[k_+8], h1h[k_+8], a1B1, false);\
            a2A0 = __builtin_amdgcn_fdot2(w1a[k_],   h1h[k_],   a2A0, false);\
            a2A1 = __builtin_amdgcn_fdot2(w1a[k_+8], h1h[k_+8], a2A1, false);\
            a2A2 = __builtin_amdgcn_fdot2(w2a[k_],   h2h[k_],   a2A2, false);\
            a2A3 = __builtin_amdgcn_fdot2(w2a[k_+8], h2h[k_+8], a2A3, false);\
            a2B0 = __builtin_amdgcn_fdot2(w1b[k_],   h1h[k_],   a2B0, false);\
            a2B1 = __builtin_amdgcn_fdot2(w1b[k_+8], h1h[k_+8], a2B1, false);\
            a2B2 = __builtin_amdgcn_fdot2(w2b[k_],   h2h[k_],   a2B2, false);\
            a2B3 = __builtin_amdgcn_fdot2(w2b[k_+8], h2h[k_+8], a2B3, false);\
        }                                                                    \
        const float nh1A = fmaxf(a1A0 + a1A1, 0.f);                          \
        const float nh1B = fmaxf(a1B0 + a1B1, 0.f);                          \
        const float nh2A = fmaxf((a2A0 + a2A1) + (a2A2 + a2A3), 0.f);        \
        const float nh2B = fmaxf((a2B0 + a2B1) + (a2B2 + a2B3), 0.f);        \
        p1[0] = (_Float16)nh1A; p1[1] = (_Float16)nh1B;                      \
        p2[0] = (_Float16)nh2A; p2[1] = (_Float16)nh2B;                      \
    }

    // ---- stage tile 0 into LDS, prefetch tile 1 ----
    STAGE(1);

    // ---- prologue t=0: h1[0] = relu(xproj(x[0])), h2[-1] = 0 ----
    {
        const float* xs = &xtile[bs][0];
        const float4 xv0 = *(const float4*)(xs);
        const float4 xv1 = *(const float4*)(xs + 4);
        const float2 xv2 = *(const float2*)(xs + 8);
        const float xvv[10] = {xv0.x, xv0.y, xv0.z, xv0.w,
                               xv1.x, xv1.y, xv1.z, xv1.w, xv2.x, xv2.y};
        float aA = bias0A, aB = bias0B;
#pragma unroll
        for (int i = 0; i < IN_; ++i) {
            aA = fmaf(wxA[i], xvv[i], aA);
            aB = fmaf(wxB[i], xvv[i], aB);
        }
        p1[0] = (_Float16)fmaxf(aA, 0.f); p1[1] = (_Float16)fmaxf(aB, 0.f);
        p2[0] = (_Float16)0.f;            p2[1] = (_Float16)0.f;
    }

    // ---- steps 1..15 (tile 0) ----
#pragma unroll 5
    for (int r = 1; r < 16; ++r) STEP(r);

    // ---- tiles 1..31 ----
#pragma unroll 1
    for (int nt = 1; nt < 32; ++nt) {
        STAGE(nt < 31);
#pragma unroll 4
        for (int r = 0; r < 16; ++r) STEP(16 * nt + r);
    }

    // ---- epilogue: h2[511] = relu(bias1 + W_ih1.h1[511] + W_hh1.h2[510]) ----
    {
        h2v h1h[16], h2h[16];
        GATH(h1h, p1)
        GATH(h2h, p2)
        float a2A0 = bias1A, a2A1 = 0.f, a2A2 = 0.f, a2A3 = 0.f;
        float a2B0 = bias1B, a2B1 = 0.f, a2B2 = 0.f, a2B3 = 0.f;
#pragma unroll
        for (int k = 0; k < 8; ++k) {
            a2A0 = __builtin_amdgcn_fdot2(w1a[k],     h1h[k],     a2A0, false);
            a2A1 = __builtin_amdgcn_fdot2(w1a[k + 8], h1h[k + 8], a2A1, false);
            a2A2 = __builtin_amdgcn_fdot2(w2a[k],     h2h[k],     a2A2, false);
            a2A3 = __builtin_amdgcn_fdot2(w2a[k + 8], h2h[k + 8], a2A3, false);
            a2B0 = __builtin_amdgcn_fdot2(w1b[k],     h1h[k],     a2B0, false);
            a2B1 = __builtin_amdgcn_fdot2(w1b[k + 8], h1h[k + 8], a2B1, false);
            a2B2 = __builtin_amdgcn_fdot2(w2b[k],     h2h[k],     a2B2, false);
            a2B3 = __builtin_amdgcn_fdot2(w2b[k + 8], h2h[k + 8], a2B3, false);
        }
        const float nh2A = fmaxf((a2A0 + a2A1) + (a2A2 + a2A3), 0.f);
        const float nh2B = fmaxf((a2B0 + a2B1) + (a2B2 + a2B3), 0.f);
        h2v pf; pf[0] = (_Float16)nh2A; pf[1] = (_Float16)nh2B;
        *(h2v*)&hfin[bs][2 * u] = pf;
        cfence();
    }

    // ---- FC head: lane u<9 computes class u for batch bs ----
    // In-wave DS RAW (in-order per-wave DS pipe) makes the hfin writes
    // visible without a barrier (proven fenceless in v6/v8).
    if (u < NC_) {
        float acc = b_fc[u];
#pragma unroll
        for (int k = 0; k < H_; ++k)
            acc = fmaf(W_fc[u * H_ + k], (float)hfin[bs][k], acc);
        out[b * NC_ + u] = acc;
    }
#undef STAGE
#undef STEP
}

extern "C" void kernel_launch(void* const* d_in, const int* in_sizes, int n_in,
                              void* d_out, int out_size, void* d_ws, size_t ws_size,
                              hipStream_t stream) {
    const float* x     = (const float*)d_in[0];
    const float* W_ih0 = (const float*)d_in[1];
    const float* W_hh0 = (const float*)d_in[2];
    const float* b_ih0 = (const float*)d_in[3];
    const float* b_hh0 = (const float*)d_in[4];
    const float* W_ih1 = (const float*)d_in[5];
    const float* W_hh1 = (const float*)d_in[6];
    const float* b_ih1 = (const float*)d_in[7];
    const float* b_hh1 = (const float*)d_in[8];
    const float* W_fc  = (const float*)d_in[9];
    const float* b_fc  = (const float*)d_in[10];
    float* out = (float*)d_out;

    const int B = in_sizes[0] / (T_ * IN_);   // 4096
    gesture_rnn_kernel<<<dim3(B / 4), dim3(64), 0, stream>>>(
        x, W_ih0, W_hh0, b_ih0, b_hh0, W_ih1, W_hh1, b_ih1, b_hh1,
        W_fc, b_fc, out);
}